// Round 1
// baseline (69.634 us; speedup 1.0000x reference)
//
#include <hip/hip_runtime.h>
#include <hip/hip_bf16.h>

#define FDIM  128
#define BATCH 4096
#define CNUM  10000

typedef __attribute__((ext_vector_type(8))) short short8;   // 8 bf16 = 4 VGPRs (MFMA A/B frag)
typedef __attribute__((ext_vector_type(4))) float f32x4;    // MFMA C/D frag

// ---------------- ws layout (bytes) ----------------
// featb : [0,          1048576)   4096*128 bf16
// wb    : [1048576,    3608576)   10000*128 bf16
// f2    : [3608576,    3624960)   4096 f32
// w2    : [3624960,    3664960)   10000 f32
// cor   : [3664960,    3681344)   4096 f32
// scale : [3681344,    3681348)   1 f32
#define WS_FEATB 0
#define WS_WB    1048576
#define WS_F2    3608576
#define WS_W2    3624960
#define WS_COR   3664960
#define WS_SCALE 3681344

// Kernel 1: convert feat+weights to bf16, compute row squared norms.
// One wave per row (14096 rows total), 2 f32 elems per lane.
__global__ void prep_kernel(const float* __restrict__ feat,
                            const float* __restrict__ weights,
                            __hip_bfloat16* __restrict__ featb,
                            __hip_bfloat16* __restrict__ wb,
                            float* __restrict__ f2,
                            float* __restrict__ w2) {
    int gw   = (blockIdx.x * blockDim.x + threadIdx.x) >> 6;
    int lane = threadIdx.x & 63;
    if (gw >= BATCH + CNUM) return;
    const float* src;
    __hip_bfloat16* dst;
    float* nrm;
    if (gw < BATCH) { src = feat    + (size_t)gw * FDIM;         dst = featb + (size_t)gw * FDIM;         nrm = f2 + gw; }
    else            { int r = gw - BATCH;
                      src = weights + (size_t)r  * FDIM;         dst = wb    + (size_t)r  * FDIM;         nrm = w2 + r;  }
    float2 v = ((const float2*)src)[lane];
    __hip_bfloat162 b2;
    b2.x = __float2bfloat16(v.x);
    b2.y = __float2bfloat16(v.y);
    ((__hip_bfloat162*)dst)[lane] = b2;
    float ss = v.x * v.x + v.y * v.y;
    #pragma unroll
    for (int off = 32; off; off >>= 1) ss += __shfl_down(ss, off, 64);
    if (lane == 0) *nrm = ss;
}

// Kernel 2: cor[i] = exp(-||feat[i]-weights[label[i]]||^2 / 1.8).
// One wave per sample; direct squared-diff (>=0, matches relu'd metric).
__global__ void cor_kernel(const float* __restrict__ feat,
                           const float* __restrict__ weights,
                           const int* __restrict__ label,
                           float* __restrict__ cor) {
    int s    = (blockIdx.x * blockDim.x + threadIdx.x) >> 6;
    int lane = threadIdx.x & 63;
    if (s >= BATCH) return;
    int lab = label[s];
    float2 f = ((const float2*)(feat    + (size_t)s   * FDIM))[lane];
    float2 w = ((const float2*)(weights + (size_t)lab * FDIM))[lane];
    float dx = f.x - w.x, dy = f.y - w.y;
    float ss = dx * dx + dy * dy;
    #pragma unroll
    for (int off = 32; off; off >>= 1) ss += __shfl_down(ss, off, 64);
    if (lane == 0) cor[s] = __expf(-ss * (1.0f / 1.8f));
}

// Kernel 3: deterministic reduction of cor -> scale = log(CNUM-1)/max(mean,0.5).
__global__ void scale_kernel(const float* __restrict__ cor, float* __restrict__ scale) {
    __shared__ float red[4];
    int t = threadIdx.x;
    float s = 0.0f;
    #pragma unroll
    for (int i = 0; i < BATCH / 256; i++) s += cor[t + i * 256];
    #pragma unroll
    for (int off = 32; off; off >>= 1) s += __shfl_down(s, off, 64);
    int wid = t >> 6, lane = t & 63;
    if (lane == 0) red[wid] = s;
    __syncthreads();
    if (t == 0) {
        float tot = red[0] + red[1] + red[2] + red[3];
        float avg = tot * (1.0f / BATCH);
        if (avg < 0.5f) avg = 0.5f;
        *scale = logf((float)(CNUM - 1)) / avg;
    }
}

// Kernel 4: main GEMM + fused epilogue.
// 128x128 tile per 256-thread block (4 waves, each wave a 64x64 sub-tile).
// K=128 in one shot: 4 k-frags of mfma_f32_16x16x32_bf16.
// Operands (3.6 MB bf16) are L2-resident -> fragments loaded straight from
// global, no LDS, no syncthreads. Epilogue: out = scale*exp(-relu(f2+w2-2d)/1.8).
__launch_bounds__(256, 2)
__global__ void gemm_kernel(const __hip_bfloat16* __restrict__ featb,
                            const __hip_bfloat16* __restrict__ wb,
                            const float* __restrict__ f2,
                            const float* __restrict__ w2,
                            const float* __restrict__ scale_p,
                            float* __restrict__ out) {
    const int MT = BATCH / 128;            // 32 row tiles
    int bid = blockIdx.x;
    int mt  = bid % MT;
    int nt  = bid / MT;                    // 79 col tiles (last partial: 16 cols)
    int tid  = threadIdx.x;
    int wid  = tid >> 6;
    int lane = tid & 63;
    int r16  = lane & 15;                  // A row / B col within fragment
    int kh   = lane >> 4;                  // k-half group (0..3)
    int rowbase = mt * 128 + (wid >> 1) * 64;
    int colbase = nt * 128 + (wid & 1) * 64;
    float scale = *scale_p;

    const short* A = (const short*)featb;
    const short* B = (const short*)wb;

    int arow[4], bcol[4];
    #pragma unroll
    for (int m = 0; m < 4; m++) arow[m] = rowbase + m * 16 + r16;
    #pragma unroll
    for (int n = 0; n < 4; n++) {
        int c = colbase + n * 16 + r16;
        bcol[n] = c < CNUM ? c : CNUM - 1;   // clamp reads; stores masked below
    }

    f32x4 acc[4][4];
    #pragma unroll
    for (int m = 0; m < 4; m++)
        #pragma unroll
        for (int n = 0; n < 4; n++) acc[m][n] = (f32x4){0.f, 0.f, 0.f, 0.f};

    #pragma unroll
    for (int kk = 0; kk < 4; kk++) {
        int ko = kk * 32 + kh * 8;         // 16B-aligned within a 256B row
        short8 a[4], b[4];
        #pragma unroll
        for (int m = 0; m < 4; m++) a[m] = *(const short8*)(A + (size_t)arow[m] * FDIM + ko);
        #pragma unroll
        for (int n = 0; n < 4; n++) b[n] = *(const short8*)(B + (size_t)bcol[n] * FDIM + ko);
        #pragma unroll
        for (int m = 0; m < 4; m++)
            #pragma unroll
            for (int n = 0; n < 4; n++)
                acc[m][n] = __builtin_amdgcn_mfma_f32_16x16x32_bf16(a[m], b[n], acc[m][n], 0, 0, 0);
    }

    // hoist f2 for the 16 rows this lane touches (C/D: col=lane&15, row=kh*4+reg)
    float f2v[4][4];
    #pragma unroll
    for (int m = 0; m < 4; m++)
        #pragma unroll
        for (int r = 0; r < 4; r++) f2v[m][r] = f2[rowbase + m * 16 + kh * 4 + r];

    #pragma unroll
    for (int n = 0; n < 4; n++) {
        int col = colbase + n * 16 + r16;
        if (col >= CNUM) continue;
        float w2v = w2[col];
        #pragma unroll
        for (int m = 0; m < 4; m++) {
            int row0 = rowbase + m * 16 + kh * 4;
            #pragma unroll
            for (int r = 0; r < 4; r++) {
                float metric = f2v[m][r] + w2v - 2.0f * acc[m][n][r];
                metric = fmaxf(metric, 0.0f);
                out[(size_t)(row0 + r) * CNUM + col] = scale * __expf(-metric * (1.0f / 1.8f));
            }
        }
    }
}

extern "C" void kernel_launch(void* const* d_in, const int* in_sizes, int n_in,
                              void* d_out, int out_size, void* d_ws, size_t ws_size,
                              hipStream_t stream) {
    (void)in_sizes; (void)n_in; (void)out_size; (void)ws_size;
    const float* feat    = (const float*)d_in[0];
    const float* weights = (const float*)d_in[1];
    const int*   label   = (const int*)d_in[2];
    float* out = (float*)d_out;
    char*  ws  = (char*)d_ws;

    __hip_bfloat16* featb = (__hip_bfloat16*)(ws + WS_FEATB);
    __hip_bfloat16* wb    = (__hip_bfloat16*)(ws + WS_WB);
    float* f2    = (float*)(ws + WS_F2);
    float* w2    = (float*)(ws + WS_W2);
    float* cor   = (float*)(ws + WS_COR);
    float* scale = (float*)(ws + WS_SCALE);

    // 1 wave/row: (4096+10000)/4 rows per 256-thread block
    prep_kernel<<<(BATCH + CNUM) / 4, 256, 0, stream>>>(feat, weights, featb, wb, f2, w2);
    cor_kernel<<<BATCH / 4, 256, 0, stream>>>(feat, weights, label, cor);
    scale_kernel<<<1, 256, 0, stream>>>(cor, scale);
    const int NT = (CNUM + 127) / 128;   // 79
    gemm_kernel<<<(BATCH / 128) * NT, 256, 0, stream>>>(featb, wb, f2, w2, scale, out);
}